// Round 1
// baseline (3257.436 us; speedup 1.0000x reference)
//
#include <hip/hip_runtime.h>
#include <math.h>

#define NS 150
#define NT 40
#define MS 200
#define MT 30
#define N_SWEEPS 10
#define JITTER 0.1f

// decode row of packed lower-triangular index t: r*(r+1)/2 + c, c<=r
__device__ __forceinline__ int tri_row(int t) {
    float f = sqrtf(8.0f * (float)t + 1.0f);
    int i = (int)((f - 1.0f) * 0.5f);
    while (((i + 1) * (i + 2)) / 2 <= t) ++i;
    while ((i * (i + 1)) / 2 > t) --i;
    return i;
}

// K1: build all four SE kernel matrices
__global__ void build_kernels(const float* __restrict__ sc, const float* __restrict__ tc,
                              const float* __restrict__ tsc, const float* __restrict__ ttc,
                              const float* __restrict__ lll, const float* __restrict__ lle,
                              const float* __restrict__ llt,
                              float* __restrict__ S, float* __restrict__ T,
                              float* __restrict__ Ts, float* __restrict__ Tt) {
    int idx = blockIdx.x * blockDim.x + threadIdx.x;
    float inv_ll2 = expf(-2.0f * lll[0]);
    float inv_le2 = expf(-2.0f * lle[0]);
    float inv_lt2 = expf(-2.0f * llt[0]);
    if (idx < NS * NS) {
        int i = idx / NS, j = idx % NS;
        float d0 = sc[i*3+0] - sc[j*3+0];
        float d1 = sc[i*3+1] - sc[j*3+1];
        float d2 = sc[i*3+2] - sc[j*3+2];
        float v = expf(-((d0*d0 + d1*d1) * inv_ll2 + d2*d2 * inv_le2));
        if (i == j) v += JITTER;
        S[idx] = v;
    } else if (idx < NS*NS + NT*NT) {
        int k = idx - NS*NS;
        int i = k / NT, j = k % NT;
        float dt = tc[i] - tc[j];
        float v = expf(-(dt*dt) * inv_lt2);
        if (i == j) v += JITTER;
        T[k] = v;
    } else if (idx < NS*NS + NT*NT + MS*NS) {
        int k = idx - NS*NS - NT*NT;
        int i = k / NS, j = k % NS;
        float d0 = tsc[i*3+0] - sc[j*3+0];
        float d1 = tsc[i*3+1] - sc[j*3+1];
        float d2 = tsc[i*3+2] - sc[j*3+2];
        Ts[k] = expf(-((d0*d0 + d1*d1) * inv_ll2 + d2*d2 * inv_le2));
    } else if (idx < NS*NS + NT*NT + MS*NS + MT*NT) {
        int k = idx - NS*NS - NT*NT - MS*NS;
        int i = k / NT, j = k % NT;
        float dt = ttc[i] - tc[j];
        Tt[k] = expf(-(dt*dt) * inv_lt2);
    }
}

// K2: cyclic parallel Jacobi eigendecomposition of 40x40 symmetric T
__global__ void __launch_bounds__(64) jacobi40(const float* __restrict__ T,
                                               float* __restrict__ Vt, float* __restrict__ wt) {
    __shared__ float A[NT][NT + 1];
    __shared__ float V[NT][NT + 1];
    __shared__ float cA[NT/2], sA[NT/2];
    __shared__ int   pA[NT/2], qA[NT/2];
    int tid = threadIdx.x;
    for (int idx = tid; idx < NT*NT; idx += 64) {
        int r = idx / NT, c = idx % NT;
        A[r][c] = T[idx];
        V[r][c] = (r == c) ? 1.0f : 0.0f;
    }
    __syncthreads();
    const int rounds = N_SWEEPS * (NT - 1);
    for (int rd = 0; rd < rounds; ++rd) {
        int rr = rd % (NT - 1);
        if (tid < NT/2) {
            int i0 = tid, i1 = NT - 1 - tid;
            int p = (i0 == 0) ? 0 : ((i0 - 1 + rr) % (NT - 1)) + 1;
            int q = ((i1 - 1 + rr) % (NT - 1)) + 1;   // i1 >= 20, never 0
            if (p > q) { int tsw = p; p = q; q = tsw; }
            float app = A[p][p], aqq = A[q][q], apq = A[p][q];
            float c, s;
            if (apq == 0.0f) { c = 1.0f; s = 0.0f; }
            else {
                float tau = (aqq - app) / (2.0f * apq);
                float tt = ((tau >= 0.0f) ? 1.0f : -1.0f) / (fabsf(tau) + sqrtf(1.0f + tau*tau));
                c = rsqrtf(1.0f + tt*tt);
                s = tt * c;
            }
            pA[tid] = p; qA[tid] = q; cA[tid] = c; sA[tid] = s;
        }
        __syncthreads();
        // left: rows p,q  (A <- J^T A)
        for (int idx = tid; idx < (NT/2)*NT; idx += 64) {
            int pr = idx / NT, k = idx % NT;
            int p = pA[pr], q = qA[pr];
            float c = cA[pr], s = sA[pr];
            float ap = A[p][k], aq = A[q][k];
            A[p][k] = c*ap - s*aq;
            A[q][k] = s*ap + c*aq;
        }
        __syncthreads();
        // right: cols p,q of A and V  (A <- A J, V <- V J)
        for (int idx = tid; idx < (NT/2)*NT; idx += 64) {
            int pr = idx / NT, k = idx % NT;
            int p = pA[pr], q = qA[pr];
            float c = cA[pr], s = sA[pr];
            float ap = A[k][p], aq = A[k][q];
            A[k][p] = c*ap - s*aq;
            A[k][q] = s*ap + c*aq;
            float vp = V[k][p], vq = V[k][q];
            V[k][p] = c*vp - s*vq;
            V[k][q] = s*vp + c*vq;
        }
        __syncthreads();
    }
    for (int idx = tid; idx < NT*NT; idx += 64) {
        int r = idx / NT, c = idx % NT;
        Vt[idx] = V[r][c];
    }
    if (tid < NT) wt[tid] = A[tid][tid];
}

// K2b: A = Tt * Vt (30x40), g[j][s] = sum_t Vt[t][j] * stData[s][t] (40x150)
__global__ void small_gemms(const float* __restrict__ Tt, const float* __restrict__ Vt,
                            const float* __restrict__ stData,
                            float* __restrict__ A, float* __restrict__ g) {
    int idx = blockIdx.x * blockDim.x + threadIdx.x;
    if (idx < MT*NT) {
        int it = idx / NT, j = idx % NT;
        float s = 0.0f;
        for (int t = 0; t < NT; ++t) s += Tt[it*NT + t] * Vt[t*NT + j];
        A[idx] = s;
    } else if (idx < MT*NT + NT*NS) {
        int k = idx - MT*NT;
        int j = k / NS, sidx = k % NS;
        float s = 0.0f;
        for (int t = 0; t < NT; ++t) s += Vt[t*NT + j] * stData[sidx*NT + t];
        g[k] = s;
    }
}

// K3: per-j fused Cholesky of M_j = wt_j*S + sigma^2 I, forward solves for
//     U = L^-1 Ts^T (200 rhs) and y = L^-1 g_j, accumulating
//     q[j][is] = sum_k U[k][is]^2,  R[j][is] = sum_k U[k][is]*y[k]
__global__ void __launch_bounds__(256) chol_solve(
        const float* __restrict__ S, const float* __restrict__ Ts,
        const float* __restrict__ wt, const float* __restrict__ g,
        const float* __restrict__ lnv,
        float* __restrict__ q, float* __restrict__ R, float* __restrict__ Uws) {
    __shared__ float Lp[NS*(NS+1)/2];   // 11325 floats, packed lower tri
    __shared__ float bvec[NS], yvec[NS];
    __shared__ float qacc[MS], Racc[MS];
    int j = blockIdx.x;
    int tid = threadIdx.x;
    float wtj = wt[j];
    float nv = expf(lnv[0]);
    float* U = Uws + (size_t)j * (NS * MS);
    for (int t = tid; t < NS*(NS+1)/2; t += 256) {
        int r = tri_row(t);
        int c = t - (r*(r+1))/2;
        float v = wtj * S[r*NS + c];
        if (r == c) v += nv;
        Lp[t] = v;
    }
    for (int t = tid; t < NS; t += 256) bvec[t] = g[j*NS + t];
    for (int t = tid; t < MS; t += 256) { qacc[t] = 0.0f; Racc[t] = 0.0f; }
    for (int t = tid; t < NS*MS; t += 256) {
        int r = t / MS, c = t % MS;
        U[t] = Ts[c*NS + r];    // rhs = Ts^T
    }
    __syncthreads();
    for (int k = 0; k < NS; ++k) {
        int dk = (k*(k+1))/2 + k;
        if (tid == 0) Lp[dk] = sqrtf(Lp[dk]);
        __syncthreads();
        float invLkk = 1.0f / Lp[dk];
        for (int r = k+1+tid; r < NS; r += 256) Lp[(r*(r+1))/2 + k] *= invLkk;
        if (tid < MS) U[k*MS + tid] *= invLkk;
        if (tid == 255) yvec[k] = bvec[k] * invLkk;
        __syncthreads();
        float yk = yvec[k];
        if (tid < MS) {
            float u = U[k*MS + tid];
            qacc[tid] += u*u;
            Racc[tid] += u*yk;
        }
        int m = NS - 1 - k;
        for (int r = k+1+tid; r < NS; r += 256) bvec[r] -= Lp[(r*(r+1))/2 + k] * yk;
        int mu = m * MS;
        for (int t = tid; t < mu; t += 256) {
            int rr = k + 1 + t / MS;
            int c = t % MS;
            U[rr*MS + c] -= Lp[(rr*(rr+1))/2 + k] * U[k*MS + c];
        }
        int mt = (m*(m+1))/2;
        for (int t = tid; t < mt; t += 256) {
            int i = tri_row(t);
            int jj = t - (i*(i+1))/2;
            int r = k + 1 + i, c = k + 1 + jj;
            Lp[(r*(r+1))/2 + c] -= Lp[(r*(r+1))/2 + k] * Lp[(c*(c+1))/2 + k];
        }
        __syncthreads();
    }
    if (tid < MS) {
        q[j*MS + tid] = qacc[tid];
        R[j*MS + tid] = Racc[tid];
    }
}

// K4: outputs. yPred[is][it] = sum_j A[it][j]*R[j][is];
//              yVar [is][it] = sig2 - sum_j A[it][j]^2 * q[j][is]
__global__ void finalize(const float* __restrict__ A, const float* __restrict__ q,
                         const float* __restrict__ R, const float* __restrict__ lsv,
                         float* __restrict__ out) {
    int idx = blockIdx.x * blockDim.x + threadIdx.x;
    if (idx >= MS * MT) return;
    int is = idx / MT, it = idx % MT;
    float sp = 0.0f, sv = 0.0f;
    for (int j = 0; j < NT; ++j) {
        float a = A[it*NT + j];
        sp += a * R[j*MS + is];
        sv += a*a * q[j*MS + is];
    }
    float sigv = expf(lsv[0]);
    out[idx] = sp;
    out[MS*MT + idx] = sigv - sv;
}

extern "C" void kernel_launch(void* const* d_in, const int* in_sizes, int n_in,
                              void* d_out, int out_size, void* d_ws, size_t ws_size,
                              hipStream_t stream) {
    const float* sc  = (const float*)d_in[0];   // 150x3
    const float* tc  = (const float*)d_in[1];   // 40x1
    const float* st  = (const float*)d_in[2];   // 150x40
    const float* tsc = (const float*)d_in[3];   // 200x3
    const float* ttc = (const float*)d_in[4];   // 30x1
    const float* lll = (const float*)d_in[5];
    const float* lle = (const float*)d_in[6];
    const float* llt = (const float*)d_in[7];
    const float* lnv = (const float*)d_in[8];
    const float* lsv = (const float*)d_in[9];
    float* out = (float*)d_out;

    float* ws = (float*)d_ws;
    float* S  = ws;              // 22500
    float* T  = S  + 22500;      // 1600
    float* Ts = T  + 1600;       // 30000
    float* Tt = Ts + 30000;      // 1200
    float* Vt = Tt + 1200;       // 1600
    float* wt = Vt + 1600;       // 40
    float* A  = wt + 40;         // 1200
    float* g  = A  + 1200;       // 6000
    float* q  = g  + 6000;       // 8000
    float* R  = q  + 8000;       // 8000
    float* U  = R  + 8000;       // 40*150*200 = 1,200,000

    int total1 = NS*NS + NT*NT + MS*NS + MT*NT;   // 55300
    hipLaunchKernelGGL(build_kernels, dim3((total1 + 255)/256), dim3(256), 0, stream,
                       sc, tc, tsc, ttc, lll, lle, llt, S, T, Ts, Tt);
    hipLaunchKernelGGL(jacobi40, dim3(1), dim3(64), 0, stream, T, Vt, wt);
    int total2 = MT*NT + NT*NS;                    // 7200
    hipLaunchKernelGGL(small_gemms, dim3((total2 + 255)/256), dim3(256), 0, stream,
                       Tt, Vt, st, A, g);
    hipLaunchKernelGGL(chol_solve, dim3(NT), dim3(256), 0, stream,
                       S, Ts, wt, g, lnv, q, R, U);
    hipLaunchKernelGGL(finalize, dim3((MS*MT + 255)/256), dim3(256), 0, stream,
                       A, q, R, lsv, out);
}

// Round 2
// 1593.337 us; speedup vs baseline: 2.0444x; 2.0444x over previous
//
#include <hip/hip_runtime.h>
#include <math.h>

#define NS 150
#define NT 40
#define MS 200
#define MT 30
#define N_SWEEPS 8
#define JITTER 0.1f
#define LPACK 11552   // padded packed lower-tri floats per j (rows 16B-aligned)

// row k (cols 0..k) starts at off(k); rows padded to 4-float alignment.
// off(k) = k(k+1)/2 + 6*(k/4) + partial[k%4], partial = {0,3,5,6}
__device__ __forceinline__ int row_off(int k) {
    int rm = k & 3;
    int partial = (rm == 0) ? 0 : (rm == 1) ? 3 : (rm == 2) ? 5 : 6;
    return (k * (k + 1)) / 2 + 6 * (k >> 2) + partial;
}

// decode row of packed lower-triangular index t: r*(r+1)/2 + c, c<=r
__device__ __forceinline__ int tri_row(int t) {
    float f = sqrtf(8.0f * (float)t + 1.0f);
    int i = (int)((f - 1.0f) * 0.5f);
    while (((i + 1) * (i + 2)) / 2 <= t) ++i;
    while ((i * (i + 1)) / 2 > t) --i;
    return i;
}

// K1: build S, T, TsT (transposed test-spatial), Tt
__global__ void build_kernels(const float* __restrict__ sc, const float* __restrict__ tc,
                              const float* __restrict__ tsc, const float* __restrict__ ttc,
                              const float* __restrict__ lll, const float* __restrict__ lle,
                              const float* __restrict__ llt,
                              float* __restrict__ S, float* __restrict__ T,
                              float* __restrict__ TsT, float* __restrict__ Tt) {
    int idx = blockIdx.x * blockDim.x + threadIdx.x;
    float inv_ll2 = expf(-2.0f * lll[0]);
    float inv_le2 = expf(-2.0f * lle[0]);
    float inv_lt2 = expf(-2.0f * llt[0]);
    if (idx < NS * NS) {
        int i = idx / NS, j = idx % NS;
        float d0 = sc[i*3+0] - sc[j*3+0];
        float d1 = sc[i*3+1] - sc[j*3+1];
        float d2 = sc[i*3+2] - sc[j*3+2];
        float v = expf(-((d0*d0 + d1*d1) * inv_ll2 + d2*d2 * inv_le2));
        if (i == j) v += JITTER;
        S[idx] = v;
    } else if (idx < NS*NS + NT*NT) {
        int k = idx - NS*NS;
        int i = k / NT, j = k % NT;
        float dt = tc[i] - tc[j];
        float v = expf(-(dt*dt) * inv_lt2);
        if (i == j) v += JITTER;
        T[k] = v;
    } else if (idx < NS*NS + NT*NT + NS*MS) {
        int t = idx - NS*NS - NT*NT;
        int k = t / MS, c = t % MS;     // k: space idx, c: test idx
        float d0 = tsc[c*3+0] - sc[k*3+0];
        float d1 = tsc[c*3+1] - sc[k*3+1];
        float d2 = tsc[c*3+2] - sc[k*3+2];
        TsT[t] = expf(-((d0*d0 + d1*d1) * inv_ll2 + d2*d2 * inv_le2));
    } else if (idx < NS*NS + NT*NT + NS*MS + MT*NT) {
        int k = idx - NS*NS - NT*NT - NS*MS;
        int i = k / NT, j = k % NT;
        float dt = ttc[i] - tc[j];
        Tt[k] = expf(-(dt*dt) * inv_lt2);
    }
}

// K2: cyclic parallel Jacobi eigendecomposition of 40x40 symmetric T
__global__ void __launch_bounds__(256) jacobi40(const float* __restrict__ T,
                                                float* __restrict__ Vt, float* __restrict__ wt) {
    __shared__ float A[NT][NT + 1];
    __shared__ float V[NT][NT + 1];
    __shared__ float cA[NT/2], sA[NT/2];
    __shared__ int   pA[NT/2], qA[NT/2];
    int tid = threadIdx.x;
    for (int idx = tid; idx < NT*NT; idx += 256) {
        int r = idx / NT, c = idx % NT;
        A[r][c] = T[idx];
        V[r][c] = (r == c) ? 1.0f : 0.0f;
    }
    __syncthreads();
    const int rounds = N_SWEEPS * (NT - 1);
    for (int rd = 0; rd < rounds; ++rd) {
        int rr = rd % (NT - 1);
        if (tid < NT/2) {
            int i0 = tid, i1 = NT - 1 - tid;
            int p = (i0 == 0) ? 0 : ((i0 - 1 + rr) % (NT - 1)) + 1;
            int q = ((i1 - 1 + rr) % (NT - 1)) + 1;   // i1 >= 20, never 0
            if (p > q) { int tsw = p; p = q; q = tsw; }
            float app = A[p][p], aqq = A[q][q], apq = A[p][q];
            float c, s;
            if (apq == 0.0f) { c = 1.0f; s = 0.0f; }
            else {
                float tau = (aqq - app) / (2.0f * apq);
                float tt = ((tau >= 0.0f) ? 1.0f : -1.0f) / (fabsf(tau) + sqrtf(1.0f + tau*tau));
                c = rsqrtf(1.0f + tt*tt);
                s = tt * c;
            }
            pA[tid] = p; qA[tid] = q; cA[tid] = c; sA[tid] = s;
        }
        __syncthreads();
        // left: rows p,q  (A <- J^T A)
        for (int idx = tid; idx < (NT/2)*NT; idx += 256) {
            int pr = idx / NT, k = idx % NT;
            int p = pA[pr], q = qA[pr];
            float c = cA[pr], s = sA[pr];
            float ap = A[p][k], aq = A[q][k];
            A[p][k] = c*ap - s*aq;
            A[q][k] = s*ap + c*aq;
        }
        __syncthreads();
        // right: cols p,q of A and V
        for (int idx = tid; idx < (NT/2)*NT; idx += 256) {
            int pr = idx / NT, k = idx % NT;
            int p = pA[pr], q = qA[pr];
            float c = cA[pr], s = sA[pr];
            float ap = A[k][p], aq = A[k][q];
            A[k][p] = c*ap - s*aq;
            A[k][q] = s*ap + c*aq;
            float vp = V[k][p], vq = V[k][q];
            V[k][p] = c*vp - s*vq;
            V[k][q] = s*vp + c*vq;
        }
        __syncthreads();
    }
    for (int idx = tid; idx < NT*NT; idx += 256) {
        int r = idx / NT, c = idx % NT;
        Vt[idx] = V[r][c];
    }
    if (tid < NT) wt[tid] = A[tid][tid];
}

// K2b: A = Tt * Vt (30x40), g[j][s] = sum_t Vt[t][j] * stData[s][t] (40x150)
__global__ void small_gemms(const float* __restrict__ Tt, const float* __restrict__ Vt,
                            const float* __restrict__ stData,
                            float* __restrict__ A, float* __restrict__ g) {
    int idx = blockIdx.x * blockDim.x + threadIdx.x;
    if (idx < MT*NT) {
        int it = idx / NT, j = idx % NT;
        float s = 0.0f;
        for (int t = 0; t < NT; ++t) s += Tt[it*NT + t] * Vt[t*NT + j];
        A[idx] = s;
    } else if (idx < MT*NT + NT*NS) {
        int k = idx - MT*NT;
        int j = k / NS, sidx = k % NS;
        float s = 0.0f;
        for (int t = 0; t < NT; ++t) s += Vt[t*NT + j] * stData[sidx*NT + t];
        g[k] = s;
    }
}

// K3a: per-j Cholesky of M_j = wt_j*S + nv*I entirely in LDS (packed aligned rows),
//      plus forward solve y_j = L^-1 g_j. Writes Lg (packed), y, dinv to global.
__global__ void __launch_bounds__(256) chol_factor(
        const float* __restrict__ S, const float* __restrict__ wt,
        const float* __restrict__ g, const float* __restrict__ lnv,
        float* __restrict__ Lg, float* __restrict__ yg, float* __restrict__ dg) {
    __shared__ float Lp[LPACK];
    __shared__ float bvec[NS];
    __shared__ float sh_inv;
    int j = blockIdx.x, tid = threadIdx.x;
    float wtj = wt[j];
    float nv = expf(lnv[0]);
    for (int t = tid; t < NS*(NS+1)/2; t += 256) {
        int r = tri_row(t);
        int c = t - (r*(r+1))/2;
        float v = wtj * S[r*NS + c];
        if (r == c) v += nv;
        Lp[row_off(r) + c] = v;
    }
    for (int t = tid; t < NS; t += 256) bvec[t] = g[j*NS + t];
    __syncthreads();
    for (int k = 0; k < NS; ++k) {
        int ok = row_off(k);
        if (tid == 0) {
            float d = sqrtf(Lp[ok + k]);
            Lp[ok + k] = d;
            sh_inv = 1.0f / d;
        }
        __syncthreads();
        float inv = sh_inv;
        int r = k + 1 + tid;
        float lrk = 0.0f;
        if (r < NS) {
            lrk = Lp[row_off(r) + k] * inv;
            Lp[row_off(r) + k] = lrk;
        }
        if (tid == 0) bvec[k] = bvec[k] * inv;   // y_k solved in place
        __syncthreads();
        float yk = bvec[k];
        if (r < NS) bvec[r] -= lrk * yk;
        int m = NS - 1 - k;
        int tot = (m * (m + 1)) / 2;
        for (int t = tid; t < tot; t += 256) {
            int i = tri_row(t);
            int jj = t - (i*(i+1))/2;
            int rr = k + 1 + i, cc = k + 1 + jj;
            Lp[row_off(rr) + cc] -= Lp[row_off(rr) + k] * Lp[row_off(cc) + k];
        }
        __syncthreads();
    }
    for (int t = tid; t < LPACK; t += 256) Lg[j*LPACK + t] = Lp[t];
    for (int t = tid; t < NS; t += 256) {
        yg[j*NS + t] = bvec[t];
        dg[j*NS + t] = 1.0f / Lp[row_off(t) + t];
    }
}

// K3b: per-(j,col) forward substitution, fully unrolled, u[] in registers.
//      q[j][c] = sum_k u_k^2 ; R[j][c] = sum_k u_k y_k
__global__ void __launch_bounds__(256, 1) trsm_qr(
        const float* __restrict__ Lg, const float* __restrict__ yg,
        const float* __restrict__ dg, const float* __restrict__ TsT,
        float* __restrict__ q, float* __restrict__ R) {
    __shared__ float Lp[LPACK];
    __shared__ float yv[NS];
    __shared__ float dv[NS];
    int j = blockIdx.x, tid = threadIdx.x;
    for (int t = tid; t < LPACK; t += 256) Lp[t] = Lg[j*LPACK + t];
    for (int t = tid; t < NS; t += 256) {
        yv[t] = yg[j*NS + t];
        dv[t] = dg[j*NS + t];
    }
    __syncthreads();
    if (tid < MS) {
        float u[NS];
        float qa = 0.0f, ra = 0.0f;
        #pragma unroll
        for (int k = 0; k < NS; ++k) {
            float s = TsT[k*MS + tid];
            const int ok = row_off(k);
            #pragma unroll
            for (int i = 0; i < k; ++i) s -= Lp[ok + i] * u[i];
            float uk = s * dv[k];
            u[k] = uk;
            qa += uk * uk;
            ra += uk * yv[k];
        }
        q[j*MS + tid] = qa;
        R[j*MS + tid] = ra;
    }
}

// K4: outputs. yPred[is][it] = sum_j A[it][j]*R[j][is];
//              yVar [is][it] = sig2 - sum_j A[it][j]^2 * q[j][is]
__global__ void finalize(const float* __restrict__ A, const float* __restrict__ q,
                         const float* __restrict__ R, const float* __restrict__ lsv,
                         float* __restrict__ out) {
    int idx = blockIdx.x * blockDim.x + threadIdx.x;
    if (idx >= MS * MT) return;
    int is = idx / MT, it = idx % MT;
    float sp = 0.0f, sv = 0.0f;
    for (int j = 0; j < NT; ++j) {
        float a = A[it*NT + j];
        sp += a * R[j*MS + is];
        sv += a*a * q[j*MS + is];
    }
    float sigv = expf(lsv[0]);
    out[idx] = sp;
    out[MS*MT + idx] = sigv - sv;
}

extern "C" void kernel_launch(void* const* d_in, const int* in_sizes, int n_in,
                              void* d_out, int out_size, void* d_ws, size_t ws_size,
                              hipStream_t stream) {
    const float* sc  = (const float*)d_in[0];   // 150x3
    const float* tc  = (const float*)d_in[1];   // 40x1
    const float* st  = (const float*)d_in[2];   // 150x40
    const float* tsc = (const float*)d_in[3];   // 200x3
    const float* ttc = (const float*)d_in[4];   // 30x1
    const float* lll = (const float*)d_in[5];
    const float* lle = (const float*)d_in[6];
    const float* llt = (const float*)d_in[7];
    const float* lnv = (const float*)d_in[8];
    const float* lsv = (const float*)d_in[9];
    float* out = (float*)d_out;

    float* ws  = (float*)d_ws;
    float* S   = ws;               // 22500
    float* T   = S   + 22500;      // 1600
    float* TsT = T   + 1600;       // 30000 (150x200)
    float* Tt  = TsT + 30000;      // 1200
    float* Vt  = Tt  + 1200;       // 1600
    float* wt  = Vt  + 1600;       // 40
    float* A   = wt  + 40;         // 1200
    float* g   = A   + 1200;       // 6000
    float* q   = g   + 6000;       // 8000
    float* R   = q   + 8000;       // 8000
    float* yg  = R   + 8000;       // 6000
    float* dg  = yg  + 6000;       // 6000
    float* Lg  = dg  + 6000;       // 40*11552 = 462080

    int total1 = NS*NS + NT*NT + NS*MS + MT*NT;   // 55300
    hipLaunchKernelGGL(build_kernels, dim3((total1 + 255)/256), dim3(256), 0, stream,
                       sc, tc, tsc, ttc, lll, lle, llt, S, T, TsT, Tt);
    hipLaunchKernelGGL(jacobi40, dim3(1), dim3(256), 0, stream, T, Vt, wt);
    int total2 = MT*NT + NT*NS;                    // 7200
    hipLaunchKernelGGL(small_gemms, dim3((total2 + 255)/256), dim3(256), 0, stream,
                       Tt, Vt, st, A, g);
    hipLaunchKernelGGL(chol_factor, dim3(NT), dim3(256), 0, stream,
                       S, wt, g, lnv, Lg, yg, dg);
    hipLaunchKernelGGL(trsm_qr, dim3(NT), dim3(256), 0, stream,
                       Lg, yg, dg, TsT, q, R);
    hipLaunchKernelGGL(finalize, dim3((MS*MT + 255)/256), dim3(256), 0, stream,
                       A, q, R, lsv, out);
}

// Round 3
// 761.690 us; speedup vs baseline: 4.2766x; 2.0918x over previous
//
#include <hip/hip_runtime.h>
#include <math.h>

#define NS 150
#define LDW 152
#define NPACK 11848   // sum of padded packed upper-tri row lengths
#define NT 40
#define MS 200
#define MT 30
#define N_SWEEPS 6
#define JITTER 0.1f

// packed upper-tri storage: row r holds cols [r&~3, 152), 16B-aligned start.
// rs_off(r) = start offset of row r.
__device__ __forceinline__ int rs_off(int r) {
    int g = r >> 2, rm = r & 3;
    return LDW * r - 8 * g * (g - 1) - 4 * rm * g;
}

// K1: build S, T, TsT (spatial-major test kernel), Tt
__global__ void build_kernels(const float* __restrict__ sc, const float* __restrict__ tc,
                              const float* __restrict__ tsc, const float* __restrict__ ttc,
                              const float* __restrict__ lll, const float* __restrict__ lle,
                              const float* __restrict__ llt,
                              float* __restrict__ S, float* __restrict__ T,
                              float* __restrict__ TsT, float* __restrict__ Tt) {
    int idx = blockIdx.x * blockDim.x + threadIdx.x;
    float inv_ll2 = expf(-2.0f * lll[0]);
    float inv_le2 = expf(-2.0f * lle[0]);
    float inv_lt2 = expf(-2.0f * llt[0]);
    if (idx < NS * NS) {
        int i = idx / NS, j = idx % NS;
        float d0 = sc[i*3+0] - sc[j*3+0];
        float d1 = sc[i*3+1] - sc[j*3+1];
        float d2 = sc[i*3+2] - sc[j*3+2];
        float v = expf(-((d0*d0 + d1*d1) * inv_ll2 + d2*d2 * inv_le2));
        if (i == j) v += JITTER;
        S[idx] = v;
    } else if (idx < NS*NS + NT*NT) {
        int k = idx - NS*NS;
        int i = k / NT, j = k % NT;
        float dt = tc[i] - tc[j];
        float v = expf(-(dt*dt) * inv_lt2);
        if (i == j) v += JITTER;
        T[k] = v;
    } else if (idx < NS*NS + NT*NT + NS*MS) {
        int t = idx - NS*NS - NT*NT;
        int k = t / MS, c = t % MS;     // k: train-space idx, c: test idx
        float d0 = tsc[c*3+0] - sc[k*3+0];
        float d1 = tsc[c*3+1] - sc[k*3+1];
        float d2 = tsc[c*3+2] - sc[k*3+2];
        TsT[t] = expf(-((d0*d0 + d1*d1) * inv_ll2 + d2*d2 * inv_le2));
    } else if (idx < NS*NS + NT*NT + NS*MS + MT*NT) {
        int k = idx - NS*NS - NT*NT - NS*MS;
        int i = k / NT, j = k % NT;
        float dt = ttc[i] - tc[j];
        Tt[k] = expf(-(dt*dt) * inv_lt2);
    }
}

// K2: cyclic Jacobi eigh of 40x40 T; fused 2x2-block rotation pass (2 barriers/round).
//     Tail: Amat = Tt * V (30x40).
__global__ void __launch_bounds__(256) jacobi40(const float* __restrict__ T,
                                                const float* __restrict__ Tt,
                                                float* __restrict__ Vt, float* __restrict__ wt,
                                                float* __restrict__ Amat) {
    __shared__ float A[NT][NT + 1];
    __shared__ float V[NT][NT + 1];
    __shared__ float cA[NT/2], sA[NT/2];
    __shared__ int   pA[NT/2], qA[NT/2];
    int tid = threadIdx.x;
    for (int idx = tid; idx < NT*NT; idx += 256) {
        int r = idx / NT, c = idx % NT;
        A[r][c] = T[idx];
        V[r][c] = (r == c) ? 1.0f : 0.0f;
    }
    __syncthreads();
    const int rounds = N_SWEEPS * (NT - 1);
    for (int rd = 0; rd < rounds; ++rd) {
        int rr = rd % (NT - 1);
        if (tid < NT/2) {
            int i0 = tid, i1 = NT - 1 - tid;
            int p = (i0 == 0) ? 0 : ((i0 - 1 + rr) % (NT - 1)) + 1;
            int q = ((i1 - 1 + rr) % (NT - 1)) + 1;
            if (p > q) { int tsw = p; p = q; q = tsw; }
            float app = A[p][p], aqq = A[q][q], apq = A[p][q];
            float c, s;
            if (apq == 0.0f) { c = 1.0f; s = 0.0f; }
            else {
                float tau = (aqq - app) / (2.0f * apq);
                float tt = ((tau >= 0.0f) ? 1.0f : -1.0f) / (fabsf(tau) + sqrtf(1.0f + tau*tau));
                c = rsqrtf(1.0f + tt*tt);
                s = tt * c;
            }
            pA[tid] = p; qA[tid] = q; cA[tid] = c; sA[tid] = s;
        }
        __syncthreads();
        // fused left+right rotation: 20x20 grid of 2x2 blocks (disjoint)
        for (int t = tid; t < 400; t += 256) {
            int bi = t / 20, bj = t % 20;
            int pi = pA[bi], qi = qA[bi]; float ci = cA[bi], si = sA[bi];
            int pj = pA[bj], qj = qA[bj]; float cj = cA[bj], sj = sA[bj];
            float a00 = A[pi][pj], a01 = A[pi][qj], a10 = A[qi][pj], a11 = A[qi][qj];
            float b00 = ci*a00 - si*a10, b01 = ci*a01 - si*a11;
            float b10 = si*a00 + ci*a10, b11 = si*a01 + ci*a11;
            A[pi][pj] = cj*b00 - sj*b01; A[pi][qj] = sj*b00 + cj*b01;
            A[qi][pj] = cj*b10 - sj*b11; A[qi][qj] = sj*b10 + cj*b11;
        }
        // V <- V J (columns)
        for (int t = tid; t < 800; t += 256) {
            int bj = t / NT, k = t % NT;
            int pj = pA[bj], qj = qA[bj]; float cj = cA[bj], sj = sA[bj];
            float vp = V[k][pj], vq = V[k][qj];
            V[k][pj] = cj*vp - sj*vq; V[k][qj] = sj*vp + cj*vq;
        }
        __syncthreads();
    }
    for (int idx = tid; idx < NT*NT; idx += 256) Vt[idx] = V[idx/NT][idx%NT];
    if (tid < NT) wt[tid] = A[tid][tid];
    __syncthreads();
    for (int idx = tid; idx < MT*NT; idx += 256) {
        int it = idx / NT, j = idx % NT;
        float s = 0.0f;
        for (int t2 = 0; t2 < NT; ++t2) s += Tt[it*NT + t2] * V[t2][j];
        Amat[idx] = s;
    }
}

// K3: per-j upper Cholesky (M = U^T U) of M_j = wt_j*S + nv*I, all row accesses,
//     deferred pivot scaling (2 barriers/step). Also forward-solves y = U^-T g_j.
//     Writes packed scaled U (diag slot = 1/d) and y to global.
__global__ void __launch_bounds__(256) chol40(const float* __restrict__ S,
        const float* __restrict__ wt, const float* __restrict__ Vt,
        const float* __restrict__ st, const float* __restrict__ lnv,
        float* __restrict__ Ug, float* __restrict__ yg) {
    __shared__ __align__(16) float Mp[NPACK];
    __shared__ float arow[LDW];
    __shared__ float bv[LDW];
    __shared__ float dv[LDW];
    int j = blockIdx.x, tid = threadIdx.x;
    float wtj = wt[j];
    float nv = expf(lnv[0]);
    // init packed M (cols >= r&~3; right-pad cols 150..151 = 0; small below-diag junk ok)
    for (int idx = tid; idx < NS*LDW; idx += 256) {
        int r = idx / LDW, c = idx - r*LDW;
        int rbase = r & ~3;
        if (c < rbase) continue;
        float v = 0.0f;
        if (c < NS) v = wtj * S[r*NS + c];
        if (c == r) v += nv;
        Mp[rs_off(r) + c - rbase] = v;
    }
    // g_j -> bv
    for (int s = tid; s < NS; s += 256) {
        float acc = 0.0f;
        for (int t = 0; t < NT; ++t) acc += Vt[t*NT + j] * st[s*NT + t];
        bv[s] = acc;
    }
    __syncthreads();
    for (int k = 0; k < NS; ++k) {
        int kbase = k & ~3;
        int rowK = rs_off(k) - kbase;        // Mp[rowK + c] = raw row k, col c
        float mkk = Mp[rowK + k];            // broadcast
        float d = sqrtf(mkk);
        float dinv = 1.0f / d;
        float dinv2 = dinv * dinv;
        float tk = bv[k] * dinv2;            // y_k * dinv (raw form)
        for (int r = k + 1 + tid; r < NS; r += 256) {
            float mkr = Mp[rowK + r];
            arow[r] = mkr * dinv2;
            bv[r] -= mkr * tk;
        }
        if (tid == 0) dv[k] = dinv;
        __syncthreads();
        // trailing update: rect [k+1,150) x [cb,152), linear map, float4
        int cb = (k + 1) & ~3;
        int W4 = (LDW - cb) >> 2;
        int qd = tid / W4;
        int ci = tid - qd * W4;
        int r = k + 1 + qd;
        int dr = 256 / W4, dc = 256 - dr * W4;
        while (r < NS) {
            int C = cb + (ci << 2);
            int rbase = r & ~3;
            if (C >= rbase) {
                int g = r >> 2, rm = r & 3;
                int addr = LDW*r - 8*g*(g-1) - 4*rm*g + C - rbase;
                float4 v = *(float4*)&Mp[addr];
                float4 mk = *(float4*)&Mp[rowK + C];
                float ar = arow[r];
                v.x -= ar * mk.x; v.y -= ar * mk.y;
                v.z -= ar * mk.z; v.w -= ar * mk.w;
                *(float4*)&Mp[addr] = v;
            }
            ci += dc; r += dr;
            if (ci >= W4) { ci -= W4; ++r; }
        }
        __syncthreads();
    }
    // epilogue: y = bv*dinv ; write scaled U (diag = dinv)
    for (int k = tid; k < NS; k += 256) yg[j*LDW + k] = bv[k] * dv[k];
    for (int idx = tid; idx < NS*LDW; idx += 256) {
        int r = idx / LDW, c = idx - r*LDW;
        int rbase = r & ~3;
        if (c < rbase) continue;
        int t = rs_off(r) + c - rbase;
        float v = Mp[t];
        float dvr = dv[r];
        v = (c > r) ? v * dvr : ((c == r) ? dvr : v);
        Ug[(size_t)j*NPACK + t] = v;
    }
}

// K4: 160 blocks (j, 50-col group), 1 wave each. Forward solve U^T u = ts_c with
//     u[] in registers, float4 broadcast row reads. q = sum u^2, R = sum u*y.
__global__ void __launch_bounds__(64) trsm160(const float* __restrict__ Ug,
        const float* __restrict__ yg, const float* __restrict__ TsT,
        float* __restrict__ q, float* __restrict__ R) {
    __shared__ __align__(16) float Up[NPACK];
    __shared__ float yv[NS];
    int bid = blockIdx.x;
    int j = bid >> 2, grp = bid & 3;
    int lane = threadIdx.x;
    int c = grp * 50 + lane;
    bool active = (lane < 50);
    int cc = active ? c : 0;
    for (int t4 = lane * 4; t4 < NPACK; t4 += 256)
        *(float4*)&Up[t4] = *(const float4*)&Ug[(size_t)j*NPACK + t4];
    for (int t = lane; t < NS; t += 64) yv[t] = yg[j*LDW + t];
    __syncthreads();
    float u[LDW];
    #pragma unroll
    for (int k = 0; k < NS; ++k) u[k] = TsT[k*MS + cc];
    u[150] = 0.0f; u[151] = 0.0f;
    float qa = 0.0f, ra = 0.0f;
    #pragma unroll
    for (int k = 0; k < NS; ++k) {
        const int base = rs_off(k) - (k & ~3);
        float uk = u[k] * Up[base + k];      // diag slot holds 1/d
        qa += uk * uk;
        ra += uk * yv[k];
        const int kp = k + 1;
        const int ka = (kp + 3) & ~3;
        #pragma unroll
        for (int t = kp; t < ((ka < NS) ? ka : NS); ++t)
            u[t] -= Up[base + t] * uk;
        #pragma unroll
        for (int t = ka; t < NS; t += 4) {
            float4 w = *(const float4*)&Up[base + t];
            u[t+0] -= w.x * uk; u[t+1] -= w.y * uk;
            u[t+2] -= w.z * uk; u[t+3] -= w.w * uk;
        }
    }
    if (active) {
        q[j*MS + c] = qa;
        R[j*MS + c] = ra;
    }
}

// K5: outputs. yPred[is][it] = sum_j A[it][j]*R[j][is];
//              yVar [is][it] = sig2 - sum_j A[it][j]^2 * q[j][is]
__global__ void finalize(const float* __restrict__ A, const float* __restrict__ q,
                         const float* __restrict__ R, const float* __restrict__ lsv,
                         float* __restrict__ out) {
    int idx = blockIdx.x * blockDim.x + threadIdx.x;
    if (idx >= MS * MT) return;
    int is = idx / MT, it = idx % MT;
    float sp = 0.0f, sv = 0.0f;
    for (int j = 0; j < NT; ++j) {
        float a = A[it*NT + j];
        sp += a * R[j*MS + is];
        sv += a*a * q[j*MS + is];
    }
    float sigv = expf(lsv[0]);
    out[idx] = sp;
    out[MS*MT + idx] = sigv - sv;
}

extern "C" void kernel_launch(void* const* d_in, const int* in_sizes, int n_in,
                              void* d_out, int out_size, void* d_ws, size_t ws_size,
                              hipStream_t stream) {
    const float* sc  = (const float*)d_in[0];   // 150x3
    const float* tc  = (const float*)d_in[1];   // 40x1
    const float* st  = (const float*)d_in[2];   // 150x40
    const float* tsc = (const float*)d_in[3];   // 200x3
    const float* ttc = (const float*)d_in[4];   // 30x1
    const float* lll = (const float*)d_in[5];
    const float* lle = (const float*)d_in[6];
    const float* llt = (const float*)d_in[7];
    const float* lnv = (const float*)d_in[8];
    const float* lsv = (const float*)d_in[9];
    float* out = (float*)d_out;

    float* ws   = (float*)d_ws;
    float* S    = ws;                 // 22500
    float* T    = S    + 22500;       // 1600
    float* TsT  = T    + 1600;        // 30000
    float* Tt   = TsT  + 30000;       // 1200
    float* Vt   = Tt   + 1200;        // 1600
    float* wt   = Vt   + 1600;        // 40
    float* Amat = wt   + 40;          // 1200
    float* q    = Amat + 1200;        // 8000
    float* R    = q    + 8000;        // 8000
    float* yg   = R    + 8000;        // 40*152 = 6080
    float* Ug   = yg   + 6080;        // 40*11848 = 473920

    int total1 = NS*NS + NT*NT + NS*MS + MT*NT;   // 55300
    hipLaunchKernelGGL(build_kernels, dim3((total1 + 255)/256), dim3(256), 0, stream,
                       sc, tc, tsc, ttc, lll, lle, llt, S, T, TsT, Tt);
    hipLaunchKernelGGL(jacobi40, dim3(1), dim3(256), 0, stream, T, Tt, Vt, wt, Amat);
    hipLaunchKernelGGL(chol40, dim3(NT), dim3(256), 0, stream,
                       S, wt, Vt, st, lnv, Ug, yg);
    hipLaunchKernelGGL(trsm160, dim3(NT*4), dim3(64), 0, stream,
                       Ug, yg, TsT, q, R);
    hipLaunchKernelGGL(finalize, dim3((MS*MT + 255)/256), dim3(256), 0, stream,
                       Amat, q, R, lsv, out);
}